// Round 6
// baseline (2262.749 us; speedup 1.0000x reference)
//
#include <hip/hip_runtime.h>
#include <hip/hip_bf16.h>

#define NN 50000      // nodes
#define NE 500000     // edges
#define DD 128        // latent size
#define NT2 (NE / 16) // 31250 tiles of 16 edges
#define NWAVES 2048   // 256 blocks * 8 waves

typedef float  f32x4 __attribute__((ext_vector_type(4)));
typedef short  s16x8 __attribute__((ext_vector_type(8)));

struct MlpPtrs { const float* W1; const float* b1; const float* W2; const float* b2; };
struct MlpArgs { MlpPtrs m[4]; };

__device__ __forceinline__ unsigned short f2bf(float f) {
    return __builtin_bit_cast(unsigned short, __hip_bfloat16(f));  // RNE, pairs fuse to v_cvt_pk_bf16_f32
}

// ---------------------------------------------------------------------------
// Prep: W1T bf16 [m][j][k]  (transposed so W1 fragments read 8 contiguous k)
// ---------------------------------------------------------------------------
__global__ void prep_w1t_kernel(const float* __restrict__ W1a, const float* __restrict__ W1b,
                                const float* __restrict__ W1c, const float* __restrict__ W1d,
                                unsigned short* __restrict__ w1t)
{
    int idx = blockIdx.x * blockDim.x + threadIdx.x;   // 4*128*128
    if (idx >= 4 * DD * DD) return;
    int m = idx >> 14, r = idx & 16383;
    int j = r >> 7, k = r & 127;
    const float* W1 = (m == 0) ? W1a : (m == 1) ? W1b : (m == 2) ? W1c : W1d;
    w1t[idx] = f2bf(W1[k * DD + j]);
}

// ---------------------------------------------------------------------------
// Persistent-weight fused 4-MLP kernel. 256 blocks x 512 threads (1 block/CU,
// 139 KB LDS). Swapped MFMA: C[j][e] = W1T x X; 16 edges per wave-tile so the
// whole live set (st[8] staging + xf[4] + acc2[10]) fits the 128-VGPR cap the
// allocator imposes on this block shape -> zero scratch.
// ---------------------------------------------------------------------------
__global__ __launch_bounds__(512, 1) void mlp_persist_kernel(
    const float* __restrict__ latent, const unsigned short* __restrict__ w1t,
    const float* __restrict__ va, const float* __restrict__ vb, const float* __restrict__ vc,
    float* __restrict__ out, float* __restrict__ lam_ws, MlpArgs args)
{
    __shared__ unsigned short W1s[4 * DD * DD];   // 128 KB, swizzled 16B units
    __shared__ float W2ps[4 * DD * 4];            // 8 KB (dout padded to 4)
    __shared__ float B1s[4 * DD];                 // 2 KB
    __shared__ float B2s[16];

    constexpr int DOUT[4]  = {3, 3, 1, 3};
    constexpr int OBASE[4] = {0, 3, 6, 7};
    constexpr int B2IDX[10] = {0, 1, 2, 4, 5, 6, 8, 12, 13, 14};

    const int t = threadIdx.x;

    // ---- stage all weights (once per block) ----
    #pragma unroll
    for (int it = 0; it < 16; ++it) {             // W1: 8192 x 16B units
        const int m = it >> 2;
        const int ul = t + (it & 3) * 512;        // unit within panel, 0..2047
        const int j = ul >> 4, ku = ul & 15;
        uint4 v = *(const uint4*)(w1t + ((size_t)m * 2048 + ul) * 8);
        *(uint4*)&W1s[m * DD * DD + j * DD + ((ku ^ (j & 7)) << 3)] = v;
    }
    #pragma unroll
    for (int m = 0; m < 4; ++m) {                 // W2 padded [128][4]
        const int j = t >> 2, o = t & 3;
        float v = 0.f;
        if (o < DOUT[m]) v = args.m[m].W2[j * DOUT[m] + o];
        W2ps[m * 512 + t] = v;
        if (t < DD) B1s[m * DD + t] = args.m[m].b1[t];
        if (t < 4)  B2s[m * 4 + t] = (t < DOUT[m]) ? args.m[m].b2[t] : 0.f;
    }
    __syncthreads();

    const int wave = t >> 6, l = t & 63;
    const int lg = l >> 4, lr = l & 15;
    const int gw = blockIdx.x * 8 + wave;

    float4 st[8];                                 // staged raw X (current, then next)
    int tile = gw;
    if (tile < NT2) {
        const float* p = latent + (size_t)(tile * 16 + lr) * DD + lg * 8;
        #pragma unroll
        for (int kc = 0; kc < 4; ++kc) {
            st[kc * 2]     = *(const float4*)(p + kc * 32);
            st[kc * 2 + 1] = *(const float4*)(p + kc * 32 + 4);
        }
    }

    while (tile < NT2) {
        // ---- convert staged X -> bf16 fragments ----
        s16x8 xf[4];
        #pragma unroll
        for (int kc = 0; kc < 4; ++kc) {
            float4 u0 = st[kc * 2], u1 = st[kc * 2 + 1];
            s16x8 v;
            v[0] = (short)f2bf(u0.x); v[1] = (short)f2bf(u0.y);
            v[2] = (short)f2bf(u0.z); v[3] = (short)f2bf(u0.w);
            v[4] = (short)f2bf(u1.x); v[5] = (short)f2bf(u1.y);
            v[6] = (short)f2bf(u1.z); v[7] = (short)f2bf(u1.w);
            xf[kc] = v;
        }
        // ---- prefetch next tile (latency hides under this tile's MFMAs) ----
        const int next = tile + NWAVES;
        if (next < NT2) {
            const float* p = latent + (size_t)(next * 16 + lr) * DD + lg * 8;
            #pragma unroll
            for (int kc = 0; kc < 4; ++kc) {
                st[kc * 2]     = *(const float4*)(p + kc * 32);
                st[kc * 2 + 1] = *(const float4*)(p + kc * 32 + 4);
            }
        }

        // ---- 4 MLPs: per-jf MFMA + fused bias/relu/layer-2 ----
        float acc2[10];
        #pragma unroll
        for (int q = 0; q < 10; ++q) acc2[q] = 0.f;

        #pragma unroll
        for (int m = 0; m < 4; ++m) {
            #pragma unroll
            for (int jf = 0; jf < 8; ++jf) {
                f32x4 a0 = *(const f32x4*)&B1s[m * DD + jf * 16 + lg * 4];  // bias as C-init
                const char* wrow = (const char*)&W1s[(m * DD + jf * 16 + lr) * DD];
                #pragma unroll
                for (int kc = 0; kc < 4; ++kc) {
                    s16x8 wf = *(const s16x8*)(wrow + (((kc * 4 + lg) ^ (lr & 7)) << 4));
                    a0 = __builtin_amdgcn_mfma_f32_16x16x32_bf16(wf, xf[kc], a0, 0, 0, 0);
                }
                #pragma unroll
                for (int r = 0; r < 4; ++r) {
                    const float h = fmaxf(a0[r], 0.f);
                    const f32x4 w2 = *(const f32x4*)&W2ps[(m * DD + jf * 16 + lg * 4 + r) * 4];
                    #pragma unroll
                    for (int o = 0; o < DOUT[m]; ++o)
                        acc2[OBASE[m] + o] = fmaf(h, w2[o], acc2[OBASE[m] + o]);
                }
            }
        }

        // ---- reduce over lg groups (lanes lr, lr+16, lr+32, lr+48) ----
        float c[10];
        #pragma unroll
        for (int q = 0; q < 10; ++q) {
            float v = acc2[q];
            v += __shfl_xor(v, 16);
            v += __shfl_xor(v, 32);
            c[q] = v;
        }

        // ---- epilogue: lanes lg==0 own edge lr ----
        if (lg == 0) {
            const int e = tile * 16 + lr;
            float cc[10];
            #pragma unroll
            for (int q = 0; q < 10; ++q) cc[q] = c[q] + B2s[B2IDX[q]];
            const size_t b3 = (size_t)e * 3;
            const float ax = va[b3+0], ay = va[b3+1], az = va[b3+2];
            const float bx = vb[b3+0], by = vb[b3+1], bz = vb[b3+2];
            const float cx = vc[b3+0], cy = vc[b3+1], cz = vc[b3+2];
            const size_t o1 = (size_t)NE * 3 + b3;
            const size_t o2 = (size_t)2 * NE * 3 + b3;
            out[b3+0] = cc[0]*ax + cc[1]*bx + cc[2]*cx;
            out[b3+1] = cc[0]*ay + cc[1]*by + cc[2]*cy;
            out[b3+2] = cc[0]*az + cc[1]*bz + cc[2]*cz;
            out[o1+0] = cc[3]*ax + cc[4]*bx + cc[5]*cx;
            out[o1+1] = cc[3]*ay + cc[4]*by + cc[5]*cy;
            out[o1+2] = cc[3]*az + cc[4]*bz + cc[5]*cz;
            out[o2+0] = cc[7]*ax + cc[8]*bx + cc[9]*cx;
            out[o2+1] = cc[7]*ay + cc[8]*by + cc[9]*cy;
            out[o2+2] = cc[7]*az + cc[8]*bz + cc[9]*cz;
            lam_ws[e] = cc[6];
        }
        tile = next;
    }
}

// ---------------------------------------------------------------------------
__global__ void zero_kernel(float* __restrict__ p, int n)
{
    int i = blockIdx.x * blockDim.x + threadIdx.x;
    if (i < n) p[i] = 0.0f;
}

// pass 1: segment sums over mask_in (receivers)
__global__ void seg_sum_kernel(const int* __restrict__ idx, const int* __restrict__ edge_attr,
                               const int* __restrict__ node_type, const float* __restrict__ out,
                               float* __restrict__ sums, float* __restrict__ cnt)
{
    int e = blockIdx.x * blockDim.x + threadIdx.x;
    if (e >= NE) return;
    if (edge_attr[e] != -1) return;
    const int n = idx[e];
    if (node_type[2 * n + 1] != -1) return;
    atomicAdd(&cnt[n], 1.0f);
    #pragma unroll
    for (int tns = 0; tns < 3; ++tns)
        #pragma unroll
        for (int c2 = 0; c2 < 3; ++c2)
            atomicAdd(&sums[(size_t)tns * 3 * NN + (size_t)n * 3 + c2],
                      out[(size_t)tns * NE * 3 + (size_t)e * 3 + c2]);
}

// fused: apply receiver-mean subtraction, then accumulate sender-mask sums
__global__ void apply_r_sum_s_kernel(const int* __restrict__ senders, const int* __restrict__ receivers,
                                     const int* __restrict__ edge_attr, const int* __restrict__ node_type,
                                     float* __restrict__ out,
                                     const float* __restrict__ sIn, const float* __restrict__ cIn,
                                     float* __restrict__ sOut, float* __restrict__ cOut)
{
    int e = blockIdx.x * blockDim.x + threadIdx.x;
    if (e >= NE) return;
    if (edge_attr[e] != -1) return;                // both masks require virtual
    const int r = receivers[e], s = senders[e];
    const bool mr = (node_type[2 * r + 1] == -1);
    const bool ms = (node_type[2 * s + 1] == -1);
    if (!mr && !ms) return;
    float v[9];
    #pragma unroll
    for (int tns = 0; tns < 3; ++tns)
        #pragma unroll
        for (int c2 = 0; c2 < 3; ++c2)
            v[tns * 3 + c2] = out[(size_t)tns * NE * 3 + (size_t)e * 3 + c2];
    if (mr) {
        const float ic = 1.0f / fmaxf(cIn[r], 1.0f);
        #pragma unroll
        for (int tns = 0; tns < 3; ++tns)
            #pragma unroll
            for (int c2 = 0; c2 < 3; ++c2) {
                v[tns * 3 + c2] -= sIn[(size_t)tns * 3 * NN + (size_t)r * 3 + c2] * ic;
                out[(size_t)tns * NE * 3 + (size_t)e * 3 + c2] = v[tns * 3 + c2];
            }
    }
    if (ms) {
        atomicAdd(&cOut[s], 1.0f);
        #pragma unroll
        for (int tns = 0; tns < 3; ++tns)
            #pragma unroll
            for (int c2 = 0; c2 < 3; ++c2)
                atomicAdd(&sOut[(size_t)tns * 3 * NN + (size_t)s * 3 + c2], v[tns * 3 + c2]);
    }
}

// pass-2 subtract (senders mask) fused with tau finalize
__global__ void apply_finalize_kernel(const int* __restrict__ senders, const int* __restrict__ receivers,
                                      const int* __restrict__ edge_attr, const int* __restrict__ node_type,
                                      const float* __restrict__ sp, const float* __restrict__ rp,
                                      const float* __restrict__ wn, const float* __restrict__ lam,
                                      const float* __restrict__ sums, const float* __restrict__ cnt,
                                      float* __restrict__ out)
{
    int e = blockIdx.x * blockDim.x + threadIdx.x;
    if (e >= NE) return;
    const int s = senders[e], r = receivers[e];
    const size_t b = (size_t)e * 3;
    const size_t tb = (size_t)NE * 3 + b;
    const size_t db = (size_t)2 * NE * 3 + b;
    float fx = out[b+0], fy = out[b+1], fz = out[b+2];
    float axx = out[tb+0], ayy = out[tb+1], azz = out[tb+2];
    const bool masked = (edge_attr[e] == -1) && (node_type[2 * s + 1] == -1);
    if (masked) {
        const float ic = 1.0f / fmaxf(cnt[s], 1.0f);
        fx -= sums[(size_t)0 * 3 * NN + (size_t)s * 3 + 0] * ic;
        fy -= sums[(size_t)0 * 3 * NN + (size_t)s * 3 + 1] * ic;
        fz -= sums[(size_t)0 * 3 * NN + (size_t)s * 3 + 2] * ic;
        axx -= sums[(size_t)1 * 3 * NN + (size_t)s * 3 + 0] * ic;
        ayy -= sums[(size_t)1 * 3 * NN + (size_t)s * 3 + 1] * ic;
        azz -= sums[(size_t)1 * 3 * NN + (size_t)s * 3 + 2] * ic;
        out[b+0] = fx; out[b+1] = fy; out[b+2] = fz;
        out[db+0] -= sums[(size_t)2 * 3 * NN + (size_t)s * 3 + 0] * ic;
        out[db+1] -= sums[(size_t)2 * 3 * NN + (size_t)s * 3 + 1] * ic;
        out[db+2] -= sums[(size_t)2 * 3 * NN + (size_t)s * 3 + 2] * ic;
    }
    const float wsv = wn[s], wrv = wn[r];
    const float inv = 1.0f / (wsv + wrv);
    const float spx = sp[b+0], spy = sp[b+1], spz = sp[b+2];
    const float rpx = rp[b+0], rpy = rp[b+1], rpz = rp[b+2];
    const float lx = rpx - (wsv * spx + wrv * rpx) * inv;
    const float ly = rpy - (wsv * spy + wrv * rpy) * inv;
    const float lz = rpz - (wsv * spz + wrv * rpz) * inv;
    const float lv = lam[e];
    const float gx = fx * lv, gy = fy * lv, gz = fz * lv;
    out[tb+0] = axx - (ly * gz - lz * gy);
    out[tb+1] = ayy - (lz * gx - lx * gz);
    out[tb+2] = azz - (lx * gy - ly * gx);
}

// ---------------------------------------------------------------------------
extern "C" void kernel_launch(void* const* d_in, const int* in_sizes, int n_in,
                              void* d_out, int out_size, void* d_ws, size_t ws_size,
                              hipStream_t stream)
{
    (void)in_sizes; (void)n_in; (void)out_size; (void)ws_size;

    const int* edge_index    = (const int*)d_in[0];
    const int* edge_attr     = (const int*)d_in[1];
    const int* node_type     = (const int*)d_in[2];
    const float* senders_pos = (const float*)d_in[3];
    const float* recv_pos    = (const float*)d_in[4];
    const float* vector_a    = (const float*)d_in[5];
    const float* vector_b    = (const float*)d_in[6];
    const float* vector_c    = (const float*)d_in[7];
    const float* latent      = (const float*)d_in[8];
    const float* w_nodes     = (const float*)d_in[9];

    MlpArgs ma;
    for (int i = 0; i < 4; ++i) {
        ma.m[i].W1 = (const float*)d_in[10 + i * 4 + 0];
        ma.m[i].b1 = (const float*)d_in[10 + i * 4 + 1];
        ma.m[i].W2 = (const float*)d_in[10 + i * 4 + 2];
        ma.m[i].b2 = (const float*)d_in[10 + i * 4 + 3];
    }

    float* out = (float*)d_out;
    // ws (floats): [lambda NE][sIn 9N][cIn N][sOut 9N][cOut N][w1t 32768 f-equiv]
    float* lam    = (float*)d_ws;
    float* segbuf = lam + NE;
    float* sIn    = segbuf;
    float* cIn    = sIn + 9 * NN;
    float* sOut   = cIn + NN;
    float* cOut   = sOut + 9 * NN;
    unsigned short* w1t = (unsigned short*)(cOut + NN);

    const int* senders   = edge_index;
    const int* receivers = edge_index + NE;

    hipLaunchKernelGGL(prep_w1t_kernel, dim3((4 * DD * DD + 255) / 256), dim3(256), 0, stream,
                       ma.m[0].W1, ma.m[1].W1, ma.m[2].W1, ma.m[3].W1, w1t);
    hipLaunchKernelGGL(zero_kernel, dim3((20 * NN + 255) / 256), dim3(256), 0, stream,
                       segbuf, 20 * NN);
    hipLaunchKernelGGL(mlp_persist_kernel, dim3(256), dim3(512), 0, stream,
                       latent, w1t, vector_a, vector_b, vector_c, out, lam, ma);
    dim3 gE((NE + 255) / 256);
    hipLaunchKernelGGL(seg_sum_kernel,       gE, dim3(256), 0, stream, receivers, edge_attr, node_type, out, sIn, cIn);
    hipLaunchKernelGGL(apply_r_sum_s_kernel, gE, dim3(256), 0, stream, senders, receivers, edge_attr, node_type,
                       out, sIn, cIn, sOut, cOut);
    hipLaunchKernelGGL(apply_finalize_kernel, gE, dim3(256), 0, stream, senders, receivers, edge_attr, node_type,
                       senders_pos, recv_pos, w_nodes, lam, sOut, cOut, out);
}

// Round 7
// 1347.722 us; speedup vs baseline: 1.6789x; 1.6789x over previous
//
#include <hip/hip_runtime.h>
#include <hip/hip_bf16.h>

#define NN 50000     // nodes
#define NE 500000    // edges
#define DD 128       // latent size
#define NT (NE / 32) // 15625 tiles of 32 edges
#define NWAVES 2048  // 256 blocks * 8 waves

typedef float  f32x4 __attribute__((ext_vector_type(4)));
typedef short  s16x8 __attribute__((ext_vector_type(8)));

struct MlpPtrs { const float* W1; const float* b1; const float* W2; const float* b2; };
struct MlpArgs { MlpPtrs m[4]; };

__device__ __forceinline__ unsigned short f2bf(float f) {
    return __builtin_bit_cast(unsigned short, __hip_bfloat16(f));  // RNE, pairs fuse to v_cvt_pk_bf16_f32
}

// ---------------------------------------------------------------------------
// Prep: W1T bf16 [m][j][k]  (transposed so W1 fragments read 8 contiguous k)
// ---------------------------------------------------------------------------
__global__ void prep_w1t_kernel(const float* __restrict__ W1a, const float* __restrict__ W1b,
                                const float* __restrict__ W1c, const float* __restrict__ W1d,
                                unsigned short* __restrict__ w1t)
{
    int idx = blockIdx.x * blockDim.x + threadIdx.x;   // 4*128*128
    if (idx >= 4 * DD * DD) return;
    int m = idx >> 14, r = idx & 16383;
    int j = r >> 7, k = r & 127;
    const float* W1 = (m == 0) ? W1a : (m == 1) ? W1b : (m == 2) ? W1c : W1d;
    w1t[idx] = f2bf(W1[k * DD + j]);
}

// ---------------------------------------------------------------------------
// Persistent-weight fused 4-MLP kernel. 256 blocks x 512 threads (1 block/CU,
// 139 KB LDS -> 8 waves/CU = 2 waves/EU). amdgpu_waves_per_eu(2,2) pins the
// allocator's occupancy target so it budgets 256 VGPRs/wave instead of the
// 128-with-spill it chose in rounds 4-6 (VGPR_Count=128 + ~0.5 GB scratch).
// Swapped MFMA: C[j][e] = W1T x X; lane (lg,lr) owns edge lr(+16*ef), hidden
// rows j = jf*16 + lg*4 + r. Layer-2 fused per-jf, bias as MFMA C-init,
// coeff reduce = 2 shfl_xor. ef0 raw X prefetched across iters; ef1 JIT.
// ---------------------------------------------------------------------------
__global__ __attribute__((amdgpu_waves_per_eu(2, 2))) __launch_bounds__(512)
void mlp_persist_kernel(
    const float* __restrict__ latent, const unsigned short* __restrict__ w1t,
    const float* __restrict__ va, const float* __restrict__ vb, const float* __restrict__ vc,
    float* __restrict__ out, float* __restrict__ lam_ws, MlpArgs args)
{
    __shared__ unsigned short W1s[4 * DD * DD];   // 128 KB, swizzled 16B units
    __shared__ float W2ps[4 * DD * 4];            // 8 KB (dout padded to 4)
    __shared__ float B1s[4 * DD];                 // 2 KB
    __shared__ float B2s[16];

    constexpr int DOUT[4]  = {3, 3, 1, 3};
    constexpr int OBASE[4] = {0, 3, 6, 7};
    constexpr int B2IDX[10] = {0, 1, 2, 4, 5, 6, 8, 12, 13, 14};

    const int t = threadIdx.x;

    // ---- stage all weights (once per block) ----
    #pragma unroll
    for (int it = 0; it < 16; ++it) {             // W1: 8192 x 16B units
        const int m = it >> 2;
        const int ul = t + (it & 3) * 512;        // unit within panel, 0..2047
        const int j = ul >> 4, ku = ul & 15;
        uint4 v = *(const uint4*)(w1t + ((size_t)m * 2048 + ul) * 8);
        *(uint4*)&W1s[m * DD * DD + j * DD + ((ku ^ (j & 7)) << 3)] = v;
    }
    #pragma unroll
    for (int m = 0; m < 4; ++m) {                 // W2 padded [128][4]
        const int j = t >> 2, o = t & 3;
        float v = 0.f;
        if (o < DOUT[m]) v = args.m[m].W2[j * DOUT[m] + o];
        W2ps[m * 512 + t] = v;
        if (t < DD) B1s[m * DD + t] = args.m[m].b1[t];
        if (t < 4)  B2s[m * 4 + t] = (t < DOUT[m]) ? args.m[m].b2[t] : 0.f;
    }
    __syncthreads();

    const int wave = t >> 6, l = t & 63;
    const int lg = l >> 4, lr = l & 15;
    const int gw = blockIdx.x * 8 + wave;

    float b2r[10];
    #pragma unroll
    for (int q = 0; q < 10; ++q) b2r[q] = B2s[B2IDX[q]];

    // per-lane swizzled byte offsets for W1 fragment reads
    int soff[4];
    #pragma unroll
    for (int kc = 0; kc < 4; ++kc) soff[kc] = ((kc * 4 + lg) ^ (lr & 7)) << 4;

    float4 xr0[8];                                // prefetched raw X, ef0 half
    int tile = gw;
    if (tile < NT) {
        const float* p0 = latent + (size_t)(tile * 32 + lr) * DD + lg * 8;
        #pragma unroll
        for (int kc = 0; kc < 4; ++kc) {
            xr0[kc * 2]     = *(const float4*)(p0 + kc * 32);
            xr0[kc * 2 + 1] = *(const float4*)(p0 + kc * 32 + 4);
        }
    }

    while (tile < NT) {
        // ---- issue ef1 loads first (latency hides under cvt + prefetch) ----
        float4 xr1[8];
        {
            const float* p1 = latent + (size_t)(tile * 32 + 16 + lr) * DD + lg * 8;
            #pragma unroll
            for (int kc = 0; kc < 4; ++kc) {
                xr1[kc * 2]     = *(const float4*)(p1 + kc * 32);
                xr1[kc * 2 + 1] = *(const float4*)(p1 + kc * 32 + 4);
            }
        }
        // ---- convert ef0 ----
        s16x8 xf[2][4];
        #pragma unroll
        for (int kc = 0; kc < 4; ++kc) {
            float4 u0 = xr0[kc * 2], u1 = xr0[kc * 2 + 1];
            s16x8 v;
            v[0] = (short)f2bf(u0.x); v[1] = (short)f2bf(u0.y);
            v[2] = (short)f2bf(u0.z); v[3] = (short)f2bf(u0.w);
            v[4] = (short)f2bf(u1.x); v[5] = (short)f2bf(u1.y);
            v[6] = (short)f2bf(u1.z); v[7] = (short)f2bf(u1.w);
            xf[0][kc] = v;
        }
        // ---- prefetch next tile's ef0 ----
        const int next = tile + NWAVES;
        if (next < NT) {
            const float* p0 = latent + (size_t)(next * 32 + lr) * DD + lg * 8;
            #pragma unroll
            for (int kc = 0; kc < 4; ++kc) {
                xr0[kc * 2]     = *(const float4*)(p0 + kc * 32);
                xr0[kc * 2 + 1] = *(const float4*)(p0 + kc * 32 + 4);
            }
        }
        // ---- convert ef1 ----
        #pragma unroll
        for (int kc = 0; kc < 4; ++kc) {
            float4 u0 = xr1[kc * 2], u1 = xr1[kc * 2 + 1];
            s16x8 v;
            v[0] = (short)f2bf(u0.x); v[1] = (short)f2bf(u0.y);
            v[2] = (short)f2bf(u0.z); v[3] = (short)f2bf(u0.w);
            v[4] = (short)f2bf(u1.x); v[5] = (short)f2bf(u1.y);
            v[6] = (short)f2bf(u1.z); v[7] = (short)f2bf(u1.w);
            xf[1][kc] = v;
        }

        // ---- 4 MLPs: per-jf MFMA pair + fused bias/relu/layer-2 ----
        float acc2[10][2];
        #pragma unroll
        for (int q = 0; q < 10; ++q) { acc2[q][0] = 0.f; acc2[q][1] = 0.f; }

        #pragma unroll
        for (int m = 0; m < 4; ++m) {
            #pragma unroll
            for (int jf = 0; jf < 8; ++jf) {
                f32x4 b1f = *(const f32x4*)&B1s[m * DD + jf * 16 + lg * 4];
                f32x4 a0 = b1f, a1 = b1f;
                const char* wrow = (const char*)&W1s[(m * DD + jf * 16 + lr) * DD];
                #pragma unroll
                for (int kc = 0; kc < 4; ++kc) {
                    s16x8 wf = *(const s16x8*)(wrow + soff[kc]);
                    a0 = __builtin_amdgcn_mfma_f32_16x16x32_bf16(wf, xf[0][kc], a0, 0, 0, 0);
                    a1 = __builtin_amdgcn_mfma_f32_16x16x32_bf16(wf, xf[1][kc], a1, 0, 0, 0);
                }
                f32x4 w2r[4];
                #pragma unroll
                for (int r = 0; r < 4; ++r)
                    w2r[r] = *(const f32x4*)&W2ps[(m * DD + jf * 16 + lg * 4 + r) * 4];
                #pragma unroll
                for (int r = 0; r < 4; ++r) {
                    float h0 = fmaxf(a0[r], 0.f), h1 = fmaxf(a1[r], 0.f);
                    #pragma unroll
                    for (int o = 0; o < DOUT[m]; ++o) {
                        acc2[OBASE[m] + o][0] = fmaf(h0, w2r[r][o], acc2[OBASE[m] + o][0]);
                        acc2[OBASE[m] + o][1] = fmaf(h1, w2r[r][o], acc2[OBASE[m] + o][1]);
                    }
                }
            }
        }

        // ---- reduce over lg groups (lanes lr, lr+16, lr+32, lr+48) ----
        float c[10][2];
        #pragma unroll
        for (int q = 0; q < 10; ++q)
            #pragma unroll
            for (int ef = 0; ef < 2; ++ef) {
                float v = acc2[q][ef];
                v += __shfl_xor(v, 16);
                v += __shfl_xor(v, 32);
                c[q][ef] = v + b2r[q];
            }

        // ---- epilogue from registers: lanes lg<2 own edge (lg*16+lr) ----
        if (lg < 2) {
            const int e = tile * 32 + lg * 16 + lr;
            float cc[10];
            #pragma unroll
            for (int q = 0; q < 10; ++q) cc[q] = (lg == 0) ? c[q][0] : c[q][1];
            const size_t b3 = (size_t)e * 3;
            const float ax = va[b3+0], ay = va[b3+1], az = va[b3+2];
            const float bx = vb[b3+0], by = vb[b3+1], bz = vb[b3+2];
            const float cx = vc[b3+0], cy = vc[b3+1], cz = vc[b3+2];
            const size_t o1 = (size_t)NE * 3 + b3;
            const size_t o2 = (size_t)2 * NE * 3 + b3;
            out[b3+0] = cc[0]*ax + cc[1]*bx + cc[2]*cx;
            out[b3+1] = cc[0]*ay + cc[1]*by + cc[2]*cy;
            out[b3+2] = cc[0]*az + cc[1]*bz + cc[2]*cz;
            out[o1+0] = cc[3]*ax + cc[4]*bx + cc[5]*cx;
            out[o1+1] = cc[3]*ay + cc[4]*by + cc[5]*cy;
            out[o1+2] = cc[3]*az + cc[4]*bz + cc[5]*cz;
            out[o2+0] = cc[7]*ax + cc[8]*bx + cc[9]*cx;
            out[o2+1] = cc[7]*ay + cc[8]*by + cc[9]*cy;
            out[o2+2] = cc[7]*az + cc[8]*bz + cc[9]*cz;
            lam_ws[e] = cc[6];
        }
        tile = next;
    }
}

// ---------------------------------------------------------------------------
__global__ void zero_kernel(float* __restrict__ p, int n)
{
    int i = blockIdx.x * blockDim.x + threadIdx.x;
    if (i < n) p[i] = 0.0f;
}

// pass 1: segment sums over mask_in (receivers)
__global__ void seg_sum_kernel(const int* __restrict__ idx, const int* __restrict__ edge_attr,
                               const int* __restrict__ node_type, const float* __restrict__ out,
                               float* __restrict__ sums, float* __restrict__ cnt)
{
    int e = blockIdx.x * blockDim.x + threadIdx.x;
    if (e >= NE) return;
    if (edge_attr[e] != -1) return;
    const int n = idx[e];
    if (node_type[2 * n + 1] != -1) return;
    atomicAdd(&cnt[n], 1.0f);
    #pragma unroll
    for (int tns = 0; tns < 3; ++tns)
        #pragma unroll
        for (int c2 = 0; c2 < 3; ++c2)
            atomicAdd(&sums[(size_t)tns * 3 * NN + (size_t)n * 3 + c2],
                      out[(size_t)tns * NE * 3 + (size_t)e * 3 + c2]);
}

// fused: apply receiver-mean subtraction, then accumulate sender-mask sums
__global__ void apply_r_sum_s_kernel(const int* __restrict__ senders, const int* __restrict__ receivers,
                                     const int* __restrict__ edge_attr, const int* __restrict__ node_type,
                                     float* __restrict__ out,
                                     const float* __restrict__ sIn, const float* __restrict__ cIn,
                                     float* __restrict__ sOut, float* __restrict__ cOut)
{
    int e = blockIdx.x * blockDim.x + threadIdx.x;
    if (e >= NE) return;
    if (edge_attr[e] != -1) return;                // both masks require virtual
    const int r = receivers[e], s = senders[e];
    const bool mr = (node_type[2 * r + 1] == -1);
    const bool ms = (node_type[2 * s + 1] == -1);
    if (!mr && !ms) return;
    float v[9];
    #pragma unroll
    for (int tns = 0; tns < 3; ++tns)
        #pragma unroll
        for (int c2 = 0; c2 < 3; ++c2)
            v[tns * 3 + c2] = out[(size_t)tns * NE * 3 + (size_t)e * 3 + c2];
    if (mr) {
        const float ic = 1.0f / fmaxf(cIn[r], 1.0f);
        #pragma unroll
        for (int tns = 0; tns < 3; ++tns)
            #pragma unroll
            for (int c2 = 0; c2 < 3; ++c2) {
                v[tns * 3 + c2] -= sIn[(size_t)tns * 3 * NN + (size_t)r * 3 + c2] * ic;
                out[(size_t)tns * NE * 3 + (size_t)e * 3 + c2] = v[tns * 3 + c2];
            }
    }
    if (ms) {
        atomicAdd(&cOut[s], 1.0f);
        #pragma unroll
        for (int tns = 0; tns < 3; ++tns)
            #pragma unroll
            for (int c2 = 0; c2 < 3; ++c2)
                atomicAdd(&sOut[(size_t)tns * 3 * NN + (size_t)s * 3 + c2], v[tns * 3 + c2]);
    }
}

// pass-2 subtract (senders mask) fused with tau finalize
__global__ void apply_finalize_kernel(const int* __restrict__ senders, const int* __restrict__ receivers,
                                      const int* __restrict__ edge_attr, const int* __restrict__ node_type,
                                      const float* __restrict__ sp, const float* __restrict__ rp,
                                      const float* __restrict__ wn, const float* __restrict__ lam,
                                      const float* __restrict__ sums, const float* __restrict__ cnt,
                                      float* __restrict__ out)
{
    int e = blockIdx.x * blockDim.x + threadIdx.x;
    if (e >= NE) return;
    const int s = senders[e], r = receivers[e];
    const size_t b = (size_t)e * 3;
    const size_t tb = (size_t)NE * 3 + b;
    const size_t db = (size_t)2 * NE * 3 + b;
    float fx = out[b+0], fy = out[b+1], fz = out[b+2];
    float axx = out[tb+0], ayy = out[tb+1], azz = out[tb+2];
    const bool masked = (edge_attr[e] == -1) && (node_type[2 * s + 1] == -1);
    if (masked) {
        const float ic = 1.0f / fmaxf(cnt[s], 1.0f);
        fx -= sums[(size_t)0 * 3 * NN + (size_t)s * 3 + 0] * ic;
        fy -= sums[(size_t)0 * 3 * NN + (size_t)s * 3 + 1] * ic;
        fz -= sums[(size_t)0 * 3 * NN + (size_t)s * 3 + 2] * ic;
        axx -= sums[(size_t)1 * 3 * NN + (size_t)s * 3 + 0] * ic;
        ayy -= sums[(size_t)1 * 3 * NN + (size_t)s * 3 + 1] * ic;
        azz -= sums[(size_t)1 * 3 * NN + (size_t)s * 3 + 2] * ic;
        out[b+0] = fx; out[b+1] = fy; out[b+2] = fz;
        out[db+0] -= sums[(size_t)2 * 3 * NN + (size_t)s * 3 + 0] * ic;
        out[db+1] -= sums[(size_t)2 * 3 * NN + (size_t)s * 3 + 1] * ic;
        out[db+2] -= sums[(size_t)2 * 3 * NN + (size_t)s * 3 + 2] * ic;
    }
    const float wsv = wn[s], wrv = wn[r];
    const float inv = 1.0f / (wsv + wrv);
    const float spx = sp[b+0], spy = sp[b+1], spz = sp[b+2];
    const float rpx = rp[b+0], rpy = rp[b+1], rpz = rp[b+2];
    const float lx = rpx - (wsv * spx + wrv * rpx) * inv;
    const float ly = rpy - (wsv * spy + wrv * rpy) * inv;
    const float lz = rpz - (wsv * spz + wrv * rpz) * inv;
    const float lv = lam[e];
    const float gx = fx * lv, gy = fy * lv, gz = fz * lv;
    out[tb+0] = axx - (ly * gz - lz * gy);
    out[tb+1] = ayy - (lz * gx - lx * gz);
    out[tb+2] = azz - (lx * gy - ly * gx);
}

// ---------------------------------------------------------------------------
extern "C" void kernel_launch(void* const* d_in, const int* in_sizes, int n_in,
                              void* d_out, int out_size, void* d_ws, size_t ws_size,
                              hipStream_t stream)
{
    (void)in_sizes; (void)n_in; (void)out_size; (void)ws_size;

    const int* edge_index    = (const int*)d_in[0];
    const int* edge_attr     = (const int*)d_in[1];
    const int* node_type     = (const int*)d_in[2];
    const float* senders_pos = (const float*)d_in[3];
    const float* recv_pos    = (const float*)d_in[4];
    const float* vector_a    = (const float*)d_in[5];
    const float* vector_b    = (const float*)d_in[6];
    const float* vector_c    = (const float*)d_in[7];
    const float* latent      = (const float*)d_in[8];
    const float* w_nodes     = (const float*)d_in[9];

    MlpArgs ma;
    for (int i = 0; i < 4; ++i) {
        ma.m[i].W1 = (const float*)d_in[10 + i * 4 + 0];
        ma.m[i].b1 = (const float*)d_in[10 + i * 4 + 1];
        ma.m[i].W2 = (const float*)d_in[10 + i * 4 + 2];
        ma.m[i].b2 = (const float*)d_in[10 + i * 4 + 3];
    }

    float* out = (float*)d_out;
    // ws (floats): [lambda NE][sIn 9N][cIn N][sOut 9N][cOut N][w1t 32768 f-equiv]
    float* lam    = (float*)d_ws;
    float* segbuf = lam + NE;
    float* sIn    = segbuf;
    float* cIn    = sIn + 9 * NN;
    float* sOut   = cIn + NN;
    float* cOut   = sOut + 9 * NN;
    unsigned short* w1t = (unsigned short*)(cOut + NN);

    const int* senders   = edge_index;
    const int* receivers = edge_index + NE;

    hipLaunchKernelGGL(prep_w1t_kernel, dim3((4 * DD * DD + 255) / 256), dim3(256), 0, stream,
                       ma.m[0].W1, ma.m[1].W1, ma.m[2].W1, ma.m[3].W1, w1t);
    hipLaunchKernelGGL(zero_kernel, dim3((20 * NN + 255) / 256), dim3(256), 0, stream,
                       segbuf, 20 * NN);
    hipLaunchKernelGGL(mlp_persist_kernel, dim3(256), dim3(512), 0, stream,
                       latent, w1t, vector_a, vector_b, vector_c, out, lam, ma);
    dim3 gE((NE + 255) / 256);
    hipLaunchKernelGGL(seg_sum_kernel,       gE, dim3(256), 0, stream, receivers, edge_attr, node_type, out, sIn, cIn);
    hipLaunchKernelGGL(apply_r_sum_s_kernel, gE, dim3(256), 0, stream, senders, receivers, edge_attr, node_type,
                       out, sIn, cIn, sOut, cOut);
    hipLaunchKernelGGL(apply_finalize_kernel, gE, dim3(256), 0, stream, senders, receivers, edge_attr, node_type,
                       senders_pos, recv_pos, w_nodes, lam, sOut, cOut, out);
}

// Round 10
// 280.682 us; speedup vs baseline: 8.0616x; 4.8016x over previous
//
#include <hip/hip_runtime.h>
#include <hip/hip_bf16.h>

#define NN 50000     // nodes
#define NE 500000    // edges
#define DD 128       // latent size

typedef float  f32x4 __attribute__((ext_vector_type(4)));
typedef short  s16x8 __attribute__((ext_vector_type(8)));

struct MlpPtrs { const float* W1; const float* b1; const float* W2; const float* b2; int dout; int obase; };
struct MlpArgs { MlpPtrs m[4]; };

__device__ __forceinline__ unsigned short f2bf(float f) {
    unsigned int u = __builtin_bit_cast(unsigned int, f);
    u += 0x7fffu + ((u >> 16) & 1u);           // RNE
    return (unsigned short)(u >> 16);
}

// ---------------------------------------------------------------------------
// Prep: W1T bf16 [m][j][k]  (transposed so B-fragments read 8 contiguous k)
// ---------------------------------------------------------------------------
__global__ void prep_w1t_kernel(const float* __restrict__ W1a, const float* __restrict__ W1b,
                                const float* __restrict__ W1c, const float* __restrict__ W1d,
                                unsigned short* __restrict__ w1t)
{
    int idx = blockIdx.x * blockDim.x + threadIdx.x;   // 4*128*128
    if (idx >= 4 * DD * DD) return;
    int m = idx >> 14, r = idx & 16383;
    int j = r >> 7, k = r & 127;
    const float* W1 = (m == 0) ? W1a : (m == 1) ? W1b : (m == 2) ? W1c : W1d;
    w1t[idx] = f2bf(W1[k * DD + j]);
}

// ---------------------------------------------------------------------------
// Fused 4-MLP kernel with bf16 MFMA layer-1 — EXACT round-3 kernel (the only
// MLP kernel validated end-to-end incl. post-timing revalidation at speed).
// 4 waves/block, 32 edges/wave (2 M-fragments), K=128, N=128 per MLP.
// ---------------------------------------------------------------------------
__global__ __launch_bounds__(256) void mlp_mfma_kernel(
    const float* __restrict__ latent, const unsigned short* __restrict__ w1t,
    const float* __restrict__ va, const float* __restrict__ vb, const float* __restrict__ vc,
    float* __restrict__ out, float* __restrict__ lam_ws, MlpArgs args)
{
    __shared__ unsigned short Ws[DD * 136];   // 34.8 KB
    __shared__ float W2s[DD * 3];             // 1.5 KB
    __shared__ float Cf[4][32][10];           // 5 KB

    const int t = threadIdx.x;
    const int wave = t >> 6, l = t & 63;
    const int lg = l >> 4, lr = l & 15;       // 16-lane group id / lane-in-group
    const int e0 = blockIdx.x * 128 + wave * 32;

    // ---- A fragments: a[mf][kc], edge row = lr (+16*mf), k = lg*8 + kc*32 + b
    s16x8 a[2][4];
    #pragma unroll
    for (int mf = 0; mf < 2; ++mf) {
        int e = e0 + mf * 16 + lr; if (e >= NE) e = NE - 1;
        const float* src = latent + (size_t)e * DD + lg * 8;
        #pragma unroll
        for (int kc = 0; kc < 4; ++kc) {
            float4 x0 = *(const float4*)(src + kc * 32);
            float4 x1 = *(const float4*)(src + kc * 32 + 4);
            s16x8 v;
            v[0] = (short)f2bf(x0.x); v[1] = (short)f2bf(x0.y);
            v[2] = (short)f2bf(x0.z); v[3] = (short)f2bf(x0.w);
            v[4] = (short)f2bf(x1.x); v[5] = (short)f2bf(x1.y);
            v[6] = (short)f2bf(x1.z); v[7] = (short)f2bf(x1.w);
            a[mf][kc] = v;
        }
    }

    for (int m = 0; m < 4; ++m) {
        const MlpPtrs P = args.m[m];
        __syncthreads();                       // everyone done with previous Ws
        // stage W1T panel (32 KB = 2048 uint4) — coalesced dwordx4, padded ds_write
        {
            const uint4* src = (const uint4*)(w1t + m * DD * DD);
            #pragma unroll
            for (int i = 0; i < 8; ++i) {                  // 8*256 = 2048 units
                int idx16 = t + i * 256;                   // 16-byte units
                uint4 vv = src[idx16];
                int j = idx16 >> 4, k = (idx16 & 15) * 8;  // 16 units per 128-short row
                *(uint4*)&Ws[j * 136 + k] = vv;
            }
        }
        for (int i = t; i < DD * P.dout; i += 256) W2s[i] = P.W2[i];
        __syncthreads();

        // ---- layer 1: MFMA
        f32x4 acc[2][8];
        #pragma unroll
        for (int mf = 0; mf < 2; ++mf)
            #pragma unroll
            for (int nf = 0; nf < 8; ++nf) {
                f32x4 z = {0.f, 0.f, 0.f, 0.f};
                acc[mf][nf] = z;
            }
        #pragma unroll
        for (int nf = 0; nf < 8; ++nf) {
            #pragma unroll
            for (int kc = 0; kc < 4; ++kc) {
                s16x8 b = *(const s16x8*)&Ws[(lr + 16 * nf) * 136 + lg * 8 + kc * 32];
                acc[0][nf] = __builtin_amdgcn_mfma_f32_16x16x32_bf16(a[0][kc], b, acc[0][nf], 0, 0, 0);
                acc[1][nf] = __builtin_amdgcn_mfma_f32_16x16x32_bf16(a[1][kc], b, acc[1][nf], 0, 0, 0);
            }
        }
        // bias + relu  (C layout: col j = lr + 16*nf, row = mf*16 + lg*4 + r)
        #pragma unroll
        for (int nf = 0; nf < 8; ++nf) {
            float bv = P.b1[16 * nf + lr];
            #pragma unroll
            for (int mf = 0; mf < 2; ++mf)
                #pragma unroll
                for (int r = 0; r < 4; ++r)
                    acc[mf][nf][r] = fmaxf(acc[mf][nf][r] + bv, 0.f);
        }
        // ---- layer 2: coeff[e][o] = sum_j h[e][j] W2[j][o] + b2[o]
        for (int o = 0; o < P.dout; ++o) {
            float w2v[8];
            #pragma unroll
            for (int nf = 0; nf < 8; ++nf) w2v[nf] = W2s[(16 * nf + lr) * P.dout + o];
            float p[2][4];
            #pragma unroll
            for (int mf = 0; mf < 2; ++mf)
                #pragma unroll
                for (int r = 0; r < 4; ++r) {
                    float s = 0.f;
                    #pragma unroll
                    for (int nf = 0; nf < 8; ++nf) s = fmaf(acc[mf][nf][r], w2v[nf], s);
                    s += __shfl_xor(s, 8);
                    s += __shfl_xor(s, 4);
                    s += __shfl_xor(s, 2);
                    s += __shfl_xor(s, 1);
                    p[mf][r] = s;
                }
            if (lr == 0) {
                float b2v = P.b2[o];
                #pragma unroll
                for (int mf = 0; mf < 2; ++mf)
                    #pragma unroll
                    for (int r = 0; r < 4; ++r)
                        Cf[wave][mf * 16 + lg * 4 + r][P.obase + o] = p[mf][r] + b2v;
            }
        }
    }
    __syncthreads();

    // ---- epilogue: combine coeffs with vectors
    if (l < 32) {
        const int e = e0 + l;
        if (e < NE) {
            float c[10];
            #pragma unroll
            for (int q = 0; q < 10; ++q) c[q] = Cf[wave][l][q];
            const float ax = va[(size_t)e*3+0], ay = va[(size_t)e*3+1], az = va[(size_t)e*3+2];
            const float bx = vb[(size_t)e*3+0], by = vb[(size_t)e*3+1], bz = vb[(size_t)e*3+2];
            const float cx = vc[(size_t)e*3+0], cy = vc[(size_t)e*3+1], cz = vc[(size_t)e*3+2];
            const size_t o0 = (size_t)e * 3;
            const size_t o1 = (size_t)NE * 3 + o0;
            const size_t o2 = (size_t)2 * NE * 3 + o0;
            out[o0+0] = c[0]*ax + c[1]*bx + c[2]*cx;
            out[o0+1] = c[0]*ay + c[1]*by + c[2]*cy;
            out[o0+2] = c[0]*az + c[1]*bz + c[2]*cz;
            out[o1+0] = c[3]*ax + c[4]*bx + c[5]*cx;
            out[o1+1] = c[3]*ay + c[4]*by + c[5]*cy;
            out[o1+2] = c[3]*az + c[4]*bz + c[5]*cz;
            out[o2+0] = c[7]*ax + c[8]*bx + c[9]*cx;
            out[o2+1] = c[7]*ay + c[8]*by + c[9]*cy;
            out[o2+2] = c[7]*az + c[8]*bz + c[9]*cz;
            lam_ws[e] = c[6];
        }
    }
}

// ---------------------------------------------------------------------------
__global__ void zero_kernel(float* __restrict__ p, int n)
{
    int i = blockIdx.x * blockDim.x + threadIdx.x;
    if (i < n) p[i] = 0.0f;
}

// pass 1: segment sums over mask_in (receivers)
__global__ void seg_sum_kernel(const int* __restrict__ idx, const int* __restrict__ edge_attr,
                               const int* __restrict__ node_type, const float* __restrict__ out,
                               float* __restrict__ sums, float* __restrict__ cnt)
{
    int e = blockIdx.x * blockDim.x + threadIdx.x;
    if (e >= NE) return;
    if (edge_attr[e] != -1) return;
    const int n = idx[e];
    if (node_type[2 * n + 1] != -1) return;
    atomicAdd(&cnt[n], 1.0f);
    #pragma unroll
    for (int tns = 0; tns < 3; ++tns)
        #pragma unroll
        for (int c2 = 0; c2 < 3; ++c2)
            atomicAdd(&sums[(size_t)tns * 3 * NN + (size_t)n * 3 + c2],
                      out[(size_t)tns * NE * 3 + (size_t)e * 3 + c2]);
}

// fused: apply receiver-mean subtraction, then accumulate sender-mask sums
__global__ void apply_r_sum_s_kernel(const int* __restrict__ senders, const int* __restrict__ receivers,
                                     const int* __restrict__ edge_attr, const int* __restrict__ node_type,
                                     float* __restrict__ out,
                                     const float* __restrict__ sIn, const float* __restrict__ cIn,
                                     float* __restrict__ sOut, float* __restrict__ cOut)
{
    int e = blockIdx.x * blockDim.x + threadIdx.x;
    if (e >= NE) return;
    if (edge_attr[e] != -1) return;                // both masks require virtual
    const int r = receivers[e], s = senders[e];
    const bool mr = (node_type[2 * r + 1] == -1);
    const bool ms = (node_type[2 * s + 1] == -1);
    if (!mr && !ms) return;
    float v[9];
    #pragma unroll
    for (int tns = 0; tns < 3; ++tns)
        #pragma unroll
        for (int c2 = 0; c2 < 3; ++c2)
            v[tns * 3 + c2] = out[(size_t)tns * NE * 3 + (size_t)e * 3 + c2];
    if (mr) {
        const float ic = 1.0f / fmaxf(cIn[r], 1.0f);
        #pragma unroll
        for (int tns = 0; tns < 3; ++tns)
            #pragma unroll
            for (int c2 = 0; c2 < 3; ++c2) {
                v[tns * 3 + c2] -= sIn[(size_t)tns * 3 * NN + (size_t)r * 3 + c2] * ic;
                out[(size_t)tns * NE * 3 + (size_t)e * 3 + c2] = v[tns * 3 + c2];
            }
    }
    if (ms) {
        atomicAdd(&cOut[s], 1.0f);
        #pragma unroll
        for (int tns = 0; tns < 3; ++tns)
            #pragma unroll
            for (int c2 = 0; c2 < 3; ++c2)
                atomicAdd(&sOut[(size_t)tns * 3 * NN + (size_t)s * 3 + c2], v[tns * 3 + c2]);
    }
}

// pass-2 subtract (senders mask) fused with tau finalize
__global__ void apply_finalize_kernel(const int* __restrict__ senders, const int* __restrict__ receivers,
                                      const int* __restrict__ edge_attr, const int* __restrict__ node_type,
                                      const float* __restrict__ sp, const float* __restrict__ rp,
                                      const float* __restrict__ wn, const float* __restrict__ lam,
                                      const float* __restrict__ sums, const float* __restrict__ cnt,
                                      float* __restrict__ out)
{
    int e = blockIdx.x * blockDim.x + threadIdx.x;
    if (e >= NE) return;
    const int s = senders[e], r = receivers[e];
    const size_t b = (size_t)e * 3;
    const size_t tb = (size_t)NE * 3 + b;
    const size_t db = (size_t)2 * NE * 3 + b;
    float fx = out[b+0], fy = out[b+1], fz = out[b+2];
    float axx = out[tb+0], ayy = out[tb+1], azz = out[tb+2];
    const bool masked = (edge_attr[e] == -1) && (node_type[2 * s + 1] == -1);
    if (masked) {
        const float ic = 1.0f / fmaxf(cnt[s], 1.0f);
        fx -= sums[(size_t)0 * 3 * NN + (size_t)s * 3 + 0] * ic;
        fy -= sums[(size_t)0 * 3 * NN + (size_t)s * 3 + 1] * ic;
        fz -= sums[(size_t)0 * 3 * NN + (size_t)s * 3 + 2] * ic;
        axx -= sums[(size_t)1 * 3 * NN + (size_t)s * 3 + 0] * ic;
        ayy -= sums[(size_t)1 * 3 * NN + (size_t)s * 3 + 1] * ic;
        azz -= sums[(size_t)1 * 3 * NN + (size_t)s * 3 + 2] * ic;
        out[b+0] = fx; out[b+1] = fy; out[b+2] = fz;
        out[db+0] -= sums[(size_t)2 * 3 * NN + (size_t)s * 3 + 0] * ic;
        out[db+1] -= sums[(size_t)2 * 3 * NN + (size_t)s * 3 + 1] * ic;
        out[db+2] -= sums[(size_t)2 * 3 * NN + (size_t)s * 3 + 2] * ic;
    }
    const float wsv = wn[s], wrv = wn[r];
    const float inv = 1.0f / (wsv + wrv);
    const float spx = sp[b+0], spy = sp[b+1], spz = sp[b+2];
    const float rpx = rp[b+0], rpy = rp[b+1], rpz = rp[b+2];
    const float lx = rpx - (wsv * spx + wrv * rpx) * inv;
    const float ly = rpy - (wsv * spy + wrv * rpy) * inv;
    const float lz = rpz - (wsv * spz + wrv * rpz) * inv;
    const float lv = lam[e];
    const float gx = fx * lv, gy = fy * lv, gz = fz * lv;
    out[tb+0] = axx - (ly * gz - lz * gy);
    out[tb+1] = ayy - (lz * gx - lx * gz);
    out[tb+2] = azz - (lx * gy - ly * gx);
}

// ---------------------------------------------------------------------------
extern "C" void kernel_launch(void* const* d_in, const int* in_sizes, int n_in,
                              void* d_out, int out_size, void* d_ws, size_t ws_size,
                              hipStream_t stream)
{
    (void)in_sizes; (void)n_in; (void)out_size; (void)ws_size;

    const int* edge_index    = (const int*)d_in[0];
    const int* edge_attr     = (const int*)d_in[1];
    const int* node_type     = (const int*)d_in[2];
    const float* senders_pos = (const float*)d_in[3];
    const float* recv_pos    = (const float*)d_in[4];
    const float* vector_a    = (const float*)d_in[5];
    const float* vector_b    = (const float*)d_in[6];
    const float* vector_c    = (const float*)d_in[7];
    const float* latent      = (const float*)d_in[8];
    const float* w_nodes     = (const float*)d_in[9];

    MlpArgs ma;
    const int douts[4] = {3, 3, 1, 3};
    const int obase[4] = {0, 3, 6, 7};
    for (int i = 0; i < 4; ++i) {
        ma.m[i].W1 = (const float*)d_in[10 + i * 4 + 0];
        ma.m[i].b1 = (const float*)d_in[10 + i * 4 + 1];
        ma.m[i].W2 = (const float*)d_in[10 + i * 4 + 2];
        ma.m[i].b2 = (const float*)d_in[10 + i * 4 + 3];
        ma.m[i].dout = douts[i];
        ma.m[i].obase = obase[i];
    }

    float* out = (float*)d_out;
    // ws (floats): [lambda NE][sIn 9N][cIn N][sOut 9N][cOut N][w1t 32768 f-equiv]
    float* lam    = (float*)d_ws;
    float* segbuf = lam + NE;
    float* sIn    = segbuf;
    float* cIn    = sIn + 9 * NN;
    float* sOut   = cIn + NN;
    float* cOut   = sOut + 9 * NN;
    unsigned short* w1t = (unsigned short*)(cOut + NN);

    const int* senders   = edge_index;
    const int* receivers = edge_index + NE;

    hipLaunchKernelGGL(prep_w1t_kernel, dim3((4 * DD * DD + 255) / 256), dim3(256), 0, stream,
                       ma.m[0].W1, ma.m[1].W1, ma.m[2].W1, ma.m[3].W1, w1t);
    hipLaunchKernelGGL(zero_kernel, dim3((20 * NN + 255) / 256), dim3(256), 0, stream,
                       segbuf, 20 * NN);
    hipLaunchKernelGGL(mlp_mfma_kernel, dim3((NE + 127) / 128), dim3(256), 0, stream,
                       latent, w1t, vector_a, vector_b, vector_c, out, lam, ma);
    dim3 gE((NE + 255) / 256);
    hipLaunchKernelGGL(seg_sum_kernel,       gE, dim3(256), 0, stream, receivers, edge_attr, node_type, out, sIn, cIn);
    hipLaunchKernelGGL(apply_r_sum_s_kernel, gE, dim3(256), 0, stream, senders, receivers, edge_attr, node_type,
                       out, sIn, cIn, sOut, cOut);
    hipLaunchKernelGGL(apply_finalize_kernel, gE, dim3(256), 0, stream, senders, receivers, edge_attr, node_type,
                       senders_pos, recv_pos, w_nodes, lam, sOut, cOut, out);
}